// Round 1
// baseline (281.227 us; speedup 1.0000x reference)
//
#include <hip/hip_runtime.h>
#include <hip/hip_bf16.h>

// Problem: B=2, N=512, C=128, D_IN=272, D_H=256
// out[b,i,k] = sum_j tanh(bn2( relu(bn1( [x_i,x_j,adj_ij] @ W1 )) @ W2 ))[k]
//
// Decomposition:
//   h1 = P1[b,i,:] + P2[b,j,:] + adj[b,i,j,:16] @ W1a      (BN1 folded in)
//   P1t = (x_i @ W1[0:128])*s1 + t1 ; P2s = (x_j @ W1[128:256])*s1 ; W1as = W1[256:272]*s1
//   h2 = relu(h1) @ (W2 * s2) + t2   (W2sT stored transposed, bf16)
//   out = sum_j tanh(h2)

typedef short short8 __attribute__((ext_vector_type(8)));
typedef float f32x4 __attribute__((ext_vector_type(4)));

#define EPSV 1e-5f

// ws layout (in floats):
//   P1t  : [1024][256]   @ 0
//   P2s  : [1024][256]   @ 262144
//   W1as : [16][256]     @ 524288
//   s1   : [256]         @ 528384
//   t1   : [256]         @ 528640
//   t2   : [256]         @ 528896
//   W2sT : [256][256] short @ float-offset 529152 (byte 2116608, 16B aligned)
#define OFF_P2S  262144
#define OFF_W1AS 524288
#define OFF_S1   528384
#define OFF_T1   528640
#define OFF_T2   528896
#define OFF_W2ST 529152

__device__ __forceinline__ short f2bf(float f) {
    unsigned u = __builtin_bit_cast(unsigned, f);
    u += 0x7fffu + ((u >> 16) & 1u);   // round-to-nearest-even
    return (short)(u >> 16);
}

// --- prep1: BN fold scalars + W1as (adj slice of W1, s1-scaled). 1 block x 256.
__global__ void prep_scalars(const float* __restrict__ W1,
                             const float* __restrict__ g1, const float* __restrict__ b1,
                             const float* __restrict__ m1, const float* __restrict__ v1,
                             const float* __restrict__ g2, const float* __restrict__ b2,
                             const float* __restrict__ m2, const float* __restrict__ v2,
                             float* __restrict__ wsf) {
    int t = threadIdx.x;  // h index 0..255
    float s1 = g1[t] * __frsqrt_rn(v1[t] + EPSV);
    float t1 = b1[t] - m1[t] * s1;
    float s2 = g2[t] * __frsqrt_rn(v2[t] + EPSV);
    float t2 = b2[t] - m2[t] * s2;
    wsf[OFF_S1 + t] = s1;
    wsf[OFF_T1 + t] = t1;
    wsf[OFF_T2 + t] = t2;
#pragma unroll
    for (int d = 0; d < 16; ++d)
        wsf[OFF_W1AS + d * 256 + t] = W1[(256 + d) * 256 + t] * s1;
}

// --- prepW2: W2sT[k][h] = bf16(W2[h][k] * s2[k]). grid 256 blocks (k) x 256 (h).
__global__ void prep_w2(const float* __restrict__ W2,
                        const float* __restrict__ g2, const float* __restrict__ v2,
                        float* __restrict__ wsf) {
    int k = blockIdx.x, h = threadIdx.x;
    float s2 = g2[k] * __frsqrt_rn(v2[k] + EPSV);
    short* W2sT = (short*)(wsf + OFF_W2ST);
    W2sT[k * 256 + h] = f2bf(W2[h * 256 + k] * s2);
}

// --- prep2: P1t / P2s. grid 1024 blocks (b*n) x 256 threads (h).
__global__ void prep_p(const float* __restrict__ inp, const float* __restrict__ W1,
                       float* __restrict__ wsf) {
    int bn = blockIdx.x, h = threadIdx.x;
    const float* x = inp + (size_t)bn * 128;
    float a1 = 0.f, a2 = 0.f;
    for (int c = 0; c < 128; ++c) {
        float xv = x[c];
        a1 = fmaf(xv, W1[c * 256 + h], a1);
        a2 = fmaf(xv, W1[(128 + c) * 256 + h], a2);
    }
    float s1 = wsf[OFF_S1 + h], t1 = wsf[OFF_T1 + h];
    wsf[(size_t)bn * 256 + h] = a1 * s1 + t1;          // P1t
    wsf[OFF_P2S + (size_t)bn * 256 + h] = a2 * s1;     // P2s
}

// --- main: one block per (b,i). 256 threads = 4 waves. 8 j-tiles of 64.
__global__ __launch_bounds__(256, 2) void propmain(
    const float* __restrict__ adj, const float* __restrict__ wsf,
    float* __restrict__ out) {
    __shared__ short h1buf[64 * 256];   // bf16 H1 tile, XOR-swizzled (32 KB)
    __shared__ float adjb[64 * 16];     // adj tile (4 KB)

    const int bi = blockIdx.x;          // b*512 + i
    const int b = bi >> 9;
    const int t = threadIdx.x;
    const int w = t >> 6, l = t & 63, r = l & 15, q = l >> 4;

    const float* P1t = wsf;
    const float* P2s = wsf + OFF_P2S;
    const float* W1as = wsf + OFF_W1AS;
    const float* t2p = wsf + OFF_T2;
    const short* W2sT = (const short*)(wsf + OFF_W2ST);

    // phase-1 per-thread constants (thread t owns h-column t)
    float w1a[16];
#pragma unroll
    for (int d = 0; d < 16; ++d) w1a[d] = W1as[d * 256 + t];
    const float p1 = P1t[(size_t)bi * 256 + t];

    // register-resident B fragments: wave w owns output cols [w*64, w*64+64)
    short8 bB[4][8];
#pragma unroll
    for (int n = 0; n < 4; ++n) {
        const int kc = w * 64 + n * 16 + r;
#pragma unroll
        for (int s = 0; s < 8; ++s)
            bB[n][s] = *(const short8*)(W2sT + kc * 256 + s * 32 + q * 8);
    }
    float t2v[4];
#pragma unroll
    for (int n = 0; n < 4; ++n) t2v[n] = t2p[w * 64 + n * 16 + r];

    float part[4] = {0.f, 0.f, 0.f, 0.f};
    const float* adjbase = adj + (size_t)bi * 512 * 16;
    const float* P2row = P2s + (size_t)b * 512 * 256;

    for (int jt = 0; jt < 8; ++jt) {
        const int jbase = jt * 64;
        // cooperative adj tile load: 64 rows x 16 floats = 4 KB
        {
            const float4 av = *(const float4*)(adjbase + jbase * 16 + t * 4);
            *(float4*)(adjb + t * 4) = av;
        }
        __syncthreads();
        // phase 1: H1[j][t] = relu(p1 + P2s[j][t] + adj[j,:16].W1as[:,t]) -> bf16 LDS
        for (int j = 0; j < 64; ++j) {
            float accv = p1 + P2row[(size_t)(jbase + j) * 256 + t];
#pragma unroll
            for (int d = 0; d < 16; ++d)
                accv = fmaf(adjb[j * 16 + d], w1a[d], accv);
            accv = fmaxf(accv, 0.f);
            h1buf[j * 256 + (t ^ ((j & 7) << 3))] = f2bf(accv);
        }
        __syncthreads();
        // phase 2: [64x256]bf16 @ [256x64]bf16 per wave via MFMA
        f32x4 acc[4][4];
#pragma unroll
        for (int rf = 0; rf < 4; ++rf)
#pragma unroll
            for (int n = 0; n < 4; ++n) acc[rf][n] = (f32x4){0.f, 0.f, 0.f, 0.f};
#pragma unroll
        for (int s = 0; s < 8; ++s) {
            short8 aA[4];
#pragma unroll
            for (int rf = 0; rf < 4; ++rf) {
                const int row = rf * 16 + r;
                aA[rf] = *(const short8*)(h1buf + row * 256 +
                                          ((s * 32 + q * 8) ^ ((row & 7) << 3)));
            }
#pragma unroll
            for (int rf = 0; rf < 4; ++rf)
#pragma unroll
                for (int n = 0; n < 4; ++n)
                    acc[rf][n] = __builtin_amdgcn_mfma_f32_16x16x32_bf16(
                        aA[rf], bB[n][s], acc[rf][n], 0, 0, 0);
        }
        // finalize tile: y = acc + t2, tanh, sum over rows (j)
#pragma unroll
        for (int n = 0; n < 4; ++n) {
            float ps = 0.f;
#pragma unroll
            for (int rf = 0; rf < 4; ++rf)
#pragma unroll
                for (int e = 0; e < 4; ++e) {
                    const float y = acc[rf][n][e] + t2v[n];
                    const float ex = __expf(2.f * y);
                    ps += 1.f - 2.f * __builtin_amdgcn_rcpf(ex + 1.f);
                }
            part[n] += ps;
        }
        __syncthreads();
    }
    // reduce partial col-sums over q (lanes l, l^16, l^32, l^48) and store
#pragma unroll
    for (int n = 0; n < 4; ++n) {
        float v = part[n];
        v += __shfl_xor(v, 16, 64);
        v += __shfl_xor(v, 32, 64);
        if (q == 0) out[(size_t)bi * 256 + w * 64 + n * 16 + r] = v;
    }
}

extern "C" void kernel_launch(void* const* d_in, const int* in_sizes, int n_in,
                              void* d_out, int out_size, void* d_ws, size_t ws_size,
                              hipStream_t stream) {
    (void)in_sizes; (void)n_in; (void)out_size; (void)ws_size;
    const float* inputs = (const float*)d_in[0];
    const float* adj    = (const float*)d_in[1];
    const float* W1     = (const float*)d_in[2];
    const float* g1     = (const float*)d_in[3];
    const float* b1     = (const float*)d_in[4];
    const float* m1     = (const float*)d_in[5];
    const float* v1     = (const float*)d_in[6];
    const float* W2     = (const float*)d_in[7];
    const float* g2     = (const float*)d_in[8];
    const float* b2     = (const float*)d_in[9];
    const float* m2     = (const float*)d_in[10];
    const float* v2     = (const float*)d_in[11];
    float* out = (float*)d_out;
    float* wsf = (float*)d_ws;

    prep_scalars<<<1, 256, 0, stream>>>(W1, g1, b1, m1, v1, g2, b2, m2, v2, wsf);
    prep_w2<<<256, 256, 0, stream>>>(W2, g2, v2, wsf);
    prep_p<<<1024, 256, 0, stream>>>(inputs, W1, wsf);
    propmain<<<1024, 256, 0, stream>>>(adj, wsf, out);
}